// Round 4
// baseline (358.235 us; speedup 1.0000x reference)
//
#include <hip/hip_runtime.h>
#include <hip/hip_fp16.h>

typedef __attribute__((ext_vector_type(8))) _Float16 f16x8;
typedef __attribute__((ext_vector_type(8))) unsigned short u16x8;
typedef __attribute__((ext_vector_type(4))) float f32x4;

#define DEV __device__ __forceinline__

DEV unsigned short f2h(float f) {
  _Float16 h = (_Float16)f;
  return __builtin_bit_cast(unsigned short, h);
}
DEV float h2f(unsigned short u) {
  return (float)__builtin_bit_cast(_Float16, u);
}
DEV unsigned pk(float lo, float hi) {
  return (unsigned)f2h(lo) | ((unsigned)f2h(hi) << 16);
}

// ---------------------------------------------------------------- mask canon
__global__ __launch_bounds__(256) void k_mask(const unsigned* __restrict__ raw,
                                              int* __restrict__ canon) {
  __shared__ int s_gt1, s_f32;
  int t = threadIdx.x;
  if (t == 0) { s_gt1 = 0; s_f32 = 0; }
  __syncthreads();
  int gt1 = 0, fv = 0;
  for (int i = t; i < 512; i += 256) {
    unsigned v = raw[i];
    if (v == 0x3F800000u) fv = 1;
    else if (v > 1u) gt1 = 1;
  }
  if (gt1) s_gt1 = 1;
  if (fv)  s_f32 = 1;
  __syncthreads();
  int mode = s_gt1 ? 1 : (s_f32 ? 2 : 0);
  for (int i = t; i < 2048; i += 256) {
    int v;
    if (mode == 1)      v = ((const unsigned char*)raw)[i] ? 1 : 0;
    else if (mode == 2) v = (((const float*)raw)[i] != 0.f) ? 1 : 0;
    else                v = raw[i] ? 1 : 0;
    canon[i] = v;
  }
}

// ---------------------------------------------------------------- layernorm -> f16
__global__ __launch_bounds__(64) void k_ln(const float* __restrict__ s,
                                           const float* __restrict__ gamma,
                                           const float* __restrict__ beta,
                                           unsigned short* __restrict__ sn) {
  int row = blockIdx.x, l = threadIdx.x;
  const float* sr = s + (size_t)row * 512 + l * 8;
  float4 x0 = *(const float4*)sr, x1 = *(const float4*)(sr + 4);
  float sum = x0.x + x0.y + x0.z + x0.w + x1.x + x1.y + x1.z + x1.w;
  float sq  = x0.x*x0.x + x0.y*x0.y + x0.z*x0.z + x0.w*x0.w
            + x1.x*x1.x + x1.y*x1.y + x1.z*x1.z + x1.w*x1.w;
#pragma unroll
  for (int off = 32; off >= 1; off >>= 1) {
    sum += __shfl_xor(sum, off);
    sq  += __shfl_xor(sq, off);
  }
  float mu = sum * (1.f / 512.f);
  float rstd = rsqrtf(sq * (1.f / 512.f) - mu * mu + 1e-5f);
  float4 g0 = *(const float4*)(gamma + l * 8), g1 = *(const float4*)(gamma + l * 8 + 4);
  float4 b0 = *(const float4*)(beta + l * 8),  b1 = *(const float4*)(beta + l * 8 + 4);
  u16x8 o;
  o[0] = f2h((x0.x - mu) * rstd * g0.x + b0.x);
  o[1] = f2h((x0.y - mu) * rstd * g0.y + b0.y);
  o[2] = f2h((x0.z - mu) * rstd * g0.z + b0.z);
  o[3] = f2h((x0.w - mu) * rstd * g0.w + b0.w);
  o[4] = f2h((x1.x - mu) * rstd * g1.x + b1.x);
  o[5] = f2h((x1.y - mu) * rstd * g1.y + b1.y);
  o[6] = f2h((x1.z - mu) * rstd * g1.z + b1.z);
  o[7] = f2h((x1.w - mu) * rstd * g1.w + b1.w);
  *(u16x8*)(sn + (size_t)row * 512 + l * 8) = o;
}

// ---------------------------------------------------------------- GEMM body (2048x512x512)
DEV void gemm_body(const unsigned short* __restrict__ A,
                   const float* __restrict__ W,
                   const float* __restrict__ bvec,
                   void* __restrict__ outp,
                   const float* __restrict__ gate,
                   int mode, int ct, int rt) {
  int t = threadIdx.x, l = t & 63, w = t >> 6;
  __shared__ unsigned short As[128 * 40];
  __shared__ unsigned short Bs[128 * 40];
  f32x4 acc[4][4];
#pragma unroll
  for (int mt = 0; mt < 4; ++mt)
#pragma unroll
    for (int nt = 0; nt < 4; ++nt) acc[mt][nt] = (f32x4){0.f, 0.f, 0.f, 0.f};

  int arow = t >> 1, akc = (t & 1) * 16;
  int bkk = t >> 3, bc0 = (t & 7) * 16;
  int wr = w >> 1, wc = w & 1;

  for (int k0 = 0; k0 < 512; k0 += 32) {
    const u16x8* ap = (const u16x8*)(A + (size_t)(rt * 128 + arow) * 512 + k0 + akc);
    u16x8 a0 = ap[0], a1 = ap[1];
    *(u16x8*)(&As[arow * 40 + akc]) = a0;
    *(u16x8*)(&As[arow * 40 + akc + 8]) = a1;
    const float* wp = W + (size_t)(k0 + bkk) * 512 + ct * 128 + bc0;
#pragma unroll
    for (int i = 0; i < 4; ++i) {
      float4 f = *(const float4*)(wp + i * 4);
      Bs[(bc0 + i * 4 + 0) * 40 + bkk] = f2h(f.x);
      Bs[(bc0 + i * 4 + 1) * 40 + bkk] = f2h(f.y);
      Bs[(bc0 + i * 4 + 2) * 40 + bkk] = f2h(f.z);
      Bs[(bc0 + i * 4 + 3) * 40 + bkk] = f2h(f.w);
    }
    __syncthreads();
    f16x8 af[4], bf[4];
#pragma unroll
    for (int mt = 0; mt < 4; ++mt)
      af[mt] = *(const f16x8*)(&As[(wr * 64 + mt * 16 + (l & 15)) * 40 + (l >> 4) * 8]);
#pragma unroll
    for (int nt = 0; nt < 4; ++nt)
      bf[nt] = *(const f16x8*)(&Bs[(wc * 64 + nt * 16 + (l & 15)) * 40 + (l >> 4) * 8]);
#pragma unroll
    for (int mt = 0; mt < 4; ++mt)
#pragma unroll
      for (int nt = 0; nt < 4; ++nt)
        acc[mt][nt] = __builtin_amdgcn_mfma_f32_16x16x32_f16(af[mt], bf[nt], acc[mt][nt], 0, 0, 0);
    __syncthreads();
  }

#pragma unroll
  for (int mt = 0; mt < 4; ++mt)
#pragma unroll
    for (int nt = 0; nt < 4; ++nt) {
      int col = ct * 128 + wc * 64 + nt * 16 + (l & 15);
      float bv = bvec[col];
#pragma unroll
      for (int i = 0; i < 4; ++i) {
        int row = rt * 128 + wr * 64 + mt * 16 + (l >> 4) * 4 + i;
        float val = acc[mt][nt][i] + bv;
        int bb_ = row >> 10, n = row & 1023, hh = col >> 5, d = col & 31;
        if (mode == 0) {
          ((unsigned short*)outp)[(size_t)row * 512 + col] = f2h(val);
        } else if (mode == 1) {
          ((unsigned short*)outp)[(((size_t)bb_ * 16 + hh) * 1024 + n) * 32 + d] = f2h(val);
        } else if (mode == 2) {
          ((unsigned short*)outp)[(((size_t)bb_ * 16 + hh) * 32 + d) * 1024 + n] = f2h(val);
        } else if (mode == 3) {
          ((float*)outp)[(size_t)row * 512 + col] = 1.f / (1.f + __expf(-val));
        } else {
          ((float*)outp)[(size_t)row * 512 + col] = gate[(size_t)row * 512 + col] * val;
        }
      }
    }
}

__global__ __launch_bounds__(256) void k_qkvg(const unsigned short* __restrict__ A,
                                              const float* __restrict__ W0, const float* __restrict__ W1,
                                              const float* __restrict__ W2, const float* __restrict__ W3,
                                              const float* __restrict__ b0, const float* __restrict__ b1,
                                              const float* __restrict__ b2, const float* __restrict__ b3,
                                              void* o0, void* o1, void* o2, void* o3) {
  int mode = blockIdx.z;
  const float* W = (mode == 0) ? W0 : (mode == 1) ? W1 : (mode == 2) ? W2 : W3;
  const float* bv = (mode == 0) ? b0 : (mode == 1) ? b1 : (mode == 2) ? b2 : b3;
  void* o = (mode == 0) ? o0 : (mode == 1) ? o1 : (mode == 2) ? o2 : o3;
  gemm_body(A, W, bv, o, nullptr, mode, blockIdx.x, blockIdx.y);
}

__global__ __launch_bounds__(256) void k_gemm_out(const unsigned short* __restrict__ A,
                                                  const float* __restrict__ W,
                                                  const float* __restrict__ bvec,
                                                  float* __restrict__ outp,
                                                  const float* __restrict__ gate) {
  gemm_body(A, W, bvec, outp, gate, 4, blockIdx.x, blockIdx.y);
}

// ---------------------------------------------------------------- pair-bias stream
// bias[b][n][h][m] f16 = z[b,n,m,:]@Wb[:,h] + bb[h]; masked m -> -65504 sentinel.
// Grid 4096: block = half z-slab (512 m rows); 4 waves x 128 rows.
// Wave-private LDS staging (no barriers): global 1KB-contiguous loads -> regs ->
// XOR-swizzled ds_write_b128 -> conflict-free ds_read_b128 A-fragments.
__global__ __launch_bounds__(256, 4) void k_bias(const float* __restrict__ z,
                                                 const float* __restrict__ Wb,
                                                 const float* __restrict__ bbp,
                                                 const int* __restrict__ maskc,
                                                 unsigned short* __restrict__ bias) {
  int bid = blockIdx.x;             // 2*(b*1024+n) + half
  int slab = bid >> 1, half = bid & 1;
  int b = slab >> 10;
  int t = threadIdx.x, l = t & 63, w = t >> 6;
  int lane15 = l & 15, g = l >> 4;

  __shared__ float lds_[4][2048];   // 8 KB per wave
  float* wlds = lds_[w];

  // B-frag: lane holds Wb[k=ks*32+g*8+j][h=lane15]
  f16x8 wf[4];
#pragma unroll
  for (int ks = 0; ks < 4; ++ks)
#pragma unroll
    for (int j = 0; j < 8; ++j)
      wf[ks][j] = (_Float16)Wb[(ks * 32 + g * 8 + j) * 16 + lane15];
  float bbh = bbp[lane15];

  const char* zb = (const char*)(z + ((size_t)slab * 1024 + half * 512 + (size_t)w * 128) * 128);
  unsigned short* ob = bias + ((size_t)slab * 16 + lane15) * 1024;
  const int* mrow = maskc + b * 1024;

  float4 rbuf[8];
  // prologue: tile 0 -> regs -> LDS
#pragma unroll
  for (int i = 0; i < 8; ++i)
    rbuf[i] = *(const float4*)(zb + i * 1024 + l * 16);
#pragma unroll
  for (int i = 0; i < 8; ++i) {
    int lin = i * 1024 + l * 16;
    int off = lin ^ (((lin >> 9) & 7) << 4);
    *(float4*)((char*)wlds + off) = rbuf[i];
  }

  for (int t8 = 0; t8 < 8; ++t8) {
    // prefetch next tile into regs (overlaps with compute below)
    if (t8 < 7) {
      const char* tb = zb + (t8 + 1) * 8192;
#pragma unroll
      for (int i = 0; i < 8; ++i)
        rbuf[i] = *(const float4*)(tb + i * 1024 + l * 16);
    }
    // compute current tile from LDS
    f32x4 acc = (f32x4){0.f, 0.f, 0.f, 0.f};
#pragma unroll
    for (int ks = 0; ks < 4; ++ks) {
      int linA = lane15 * 512 + ks * 128 + g * 32;
      int swz = ((lane15 & 7) << 4);
      float4 z0 = *(const float4*)((const char*)wlds + (linA ^ swz));
      float4 z1 = *(const float4*)((const char*)wlds + ((linA + 16) ^ swz));
      f16x8 af;
      af[0] = (_Float16)z0.x; af[1] = (_Float16)z0.y;
      af[2] = (_Float16)z0.z; af[3] = (_Float16)z0.w;
      af[4] = (_Float16)z1.x; af[5] = (_Float16)z1.y;
      af[6] = (_Float16)z1.z; af[7] = (_Float16)z1.w;
      acc = __builtin_amdgcn_mfma_f32_16x16x32_f16(af, wf[ks], acc, 0, 0, 0);
    }
    // epilogue: C col=h=lane15, row=4g+i
    int mabs = half * 512 + w * 128 + t8 * 16 + 4 * g;
    int4 mk = *(const int4*)(mrow + mabs);
    ushort4 o4;
    o4.x = mk.x ? 0xFBFFu : f2h(acc[0] + bbh);
    o4.y = mk.y ? 0xFBFFu : f2h(acc[1] + bbh);
    o4.z = mk.z ? 0xFBFFu : f2h(acc[2] + bbh);
    o4.w = mk.w ? 0xFBFFu : f2h(acc[3] + bbh);
    *(ushort4*)(ob + mabs) = o4;
    // store prefetched tile (after all reads of current tile)
    if (t8 < 7) {
#pragma unroll
      for (int i = 0; i < 8; ++i) {
        int lin = i * 1024 + l * 16;
        int off = lin ^ (((lin >> 9) & 7) << 4);
        *(float4*)((char*)wlds + off) = rbuf[i];
      }
    }
  }
}

// ---------------------------------------------------------------- attention (in-register flash, key-split)
// Block: (qt, h, b), 8 waves: wave = (qs = w&3, key-half = w>>2). Each wave does
// 16 q-rows x 512 keys; halves merged via LDS (online-softmax state merge).
__global__ __launch_bounds__(512, 4) void k_attn(const unsigned short* __restrict__ qbuf,
                                                 const unsigned short* __restrict__ kbuf,
                                                 const unsigned short* __restrict__ vbuf,
                                                 const unsigned short* __restrict__ bias,
                                                 unsigned short* __restrict__ aout) {
  int qt = blockIdx.x, h = blockIdx.y, b = blockIdx.z;
  int t = threadIdx.x, l = t & 63, w = t >> 6;
  int qs = w & 3, half = w >> 2;
  int q0 = (qt * 4 + qs) * 16;
  int lane15 = l & 15, g = l >> 4;
  int bh = b * 16 + h;
  const float RS = 0.17677669529663687f;  // 1/sqrt(32)

  __shared__ float red_m[4][64];
  __shared__ float red_l[4][64];
  __shared__ f32x4 red_a1[4][64];
  __shared__ f32x4 red_a2[4][64];

  // Q B-frag: lane holds Q[q0+lane15][d=g*8+j]
  f16x8 qf = *(const f16x8*)(qbuf + ((size_t)(b * 1024 + q0 + lane15)) * 512 + h * 32 + g * 8);

  const unsigned short* kb_ = kbuf + (size_t)bh * 1024 * 32 + (size_t)half * 512 * 32;
  const unsigned short* vb_ = vbuf + (size_t)bh * 32 * 1024 + half * 512;
  const unsigned short* brow = bias + ((size_t)(b * 1024 + q0 + lane15) * 16 + h) * 1024 + half * 512;

  float m_run = -3.0e38f, lsum = 0.f;
  f32x4 acc1 = (f32x4){0.f, 0.f, 0.f, 0.f};
  f32x4 acc2 = (f32x4){0.f, 0.f, 0.f, 0.f};

  for (int c = 0; c < 16; ++c) {
    int m0 = c * 32;
    f16x8 kf1 = *(const f16x8*)(kb_ + (size_t)(m0 + lane15) * 32 + g * 8);
    f16x8 kf2 = *(const f16x8*)(kb_ + (size_t)(m0 + 16 + lane15) * 32 + g * 8);
    f32x4 zero = (f32x4){0.f, 0.f, 0.f, 0.f};
    f32x4 c1 = __builtin_amdgcn_mfma_f32_16x16x32_f16(kf1, qf, zero, 0, 0, 0);
    f32x4 c2 = __builtin_amdgcn_mfma_f32_16x16x32_f16(kf2, qf, zero, 0, 0, 0);
    ushort4 bv1 = *(const ushort4*)(brow + m0 + 4 * g);
    ushort4 bv2 = *(const ushort4*)(brow + m0 + 16 + 4 * g);
    float s1[4], s2[4];
    s1[0] = c1[0] * RS + h2f(bv1.x); s1[1] = c1[1] * RS + h2f(bv1.y);
    s1[2] = c1[2] * RS + h2f(bv1.z); s1[3] = c1[3] * RS + h2f(bv1.w);
    s2[0] = c2[0] * RS + h2f(bv2.x); s2[1] = c2[1] * RS + h2f(bv2.y);
    s2[2] = c2[2] * RS + h2f(bv2.z); s2[3] = c2[3] * RS + h2f(bv2.w);
    float cm = fmaxf(fmaxf(fmaxf(s1[0], s1[1]), fmaxf(s1[2], s1[3])),
                     fmaxf(fmaxf(s2[0], s2[1]), fmaxf(s2[2], s2[3])));
    cm = fmaxf(cm, __shfl_xor(cm, 16));
    cm = fmaxf(cm, __shfl_xor(cm, 32));
    float mn = fmaxf(m_run, cm);
    float corr = __expf(m_run - mn);
    m_run = mn;
    float p1[4], p2[4], csum = 0.f;
#pragma unroll
    for (int i = 0; i < 4; ++i) { p1[i] = __expf(s1[i] - mn); csum += p1[i]; }
#pragma unroll
    for (int i = 0; i < 4; ++i) { p2[i] = __expf(s2[i] - mn); csum += p2[i]; }
    lsum = lsum * corr + csum;
#pragma unroll
    for (int i = 0; i < 4; ++i) { acc1[i] *= corr; acc2[i] *= corr; }
    // repack P (C-layout) -> PV B-frag
    unsigned a0 = pk(p1[0], p1[1]), a1 = pk(p1[2], p1[3]);
    unsigned b0 = pk(p2[0], p2[1]), b1 = pk(p2[2], p2[3]);
    int s0 = ((g & 1) << 5) + lane15, s1l = s0 + 16;
    unsigned wA0 = (unsigned)__shfl((int)a0, s0);
    unsigned wA1 = (unsigned)__shfl((int)a1, s0);
    unsigned wA2 = (unsigned)__shfl((int)a0, s1l);
    unsigned wA3 = (unsigned)__shfl((int)a1, s1l);
    unsigned wB0 = (unsigned)__shfl((int)b0, s0);
    unsigned wB1 = (unsigned)__shfl((int)b1, s0);
    unsigned wB2 = (unsigned)__shfl((int)b0, s1l);
    unsigned wB3 = (unsigned)__shfl((int)b1, s1l);
    bool hi = (l & 32) != 0;
    union { unsigned u[4]; f16x8 v; } pu;
    pu.u[0] = hi ? wB0 : wA0;
    pu.u[1] = hi ? wB1 : wA1;
    pu.u[2] = hi ? wB2 : wA2;
    pu.u[3] = hi ? wB3 : wA3;
    f16x8 vf1 = *(const f16x8*)(vb_ + (size_t)lane15 * 1024 + m0 + 8 * g);
    f16x8 vf2 = *(const f16x8*)(vb_ + (size_t)(16 + lane15) * 1024 + m0 + 8 * g);
    acc1 = __builtin_amdgcn_mfma_f32_16x16x32_f16(vf1, pu.v, acc1, 0, 0, 0);
    acc2 = __builtin_amdgcn_mfma_f32_16x16x32_f16(vf2, pu.v, acc2, 0, 0, 0);
  }

  lsum += __shfl_xor(lsum, 16);
  lsum += __shfl_xor(lsum, 32);

  if (half) {
    red_m[qs][l] = m_run;
    red_l[qs][l] = lsum;
    red_a1[qs][l] = acc1;
    red_a2[qs][l] = acc2;
  }
  __syncthreads();
  if (!half) {
    float pm = red_m[qs][l], plv = red_l[qs][l];
    f32x4 pa1 = red_a1[qs][l], pa2 = red_a2[qs][l];
    float mm = fmaxf(m_run, pm);
    float c1s = __expf(m_run - mm), c2s = __expf(pm - mm);
    float lt = lsum * c1s + plv * c2s;
    float inv = (mm > -30000.f && lt > 0.f) ? 1.f / lt : 0.f;
    unsigned short* orow = aout + ((size_t)(b * 1024 + q0 + lane15)) * 512 + h * 32;
    ushort4 o1, o2;
    o1.x = f2h((acc1[0] * c1s + pa1[0] * c2s) * inv);
    o1.y = f2h((acc1[1] * c1s + pa1[1] * c2s) * inv);
    o1.z = f2h((acc1[2] * c1s + pa1[2] * c2s) * inv);
    o1.w = f2h((acc1[3] * c1s + pa1[3] * c2s) * inv);
    o2.x = f2h((acc2[0] * c1s + pa2[0] * c2s) * inv);
    o2.y = f2h((acc2[1] * c1s + pa2[1] * c2s) * inv);
    o2.z = f2h((acc2[2] * c1s + pa2[2] * c2s) * inv);
    o2.w = f2h((acc2[3] * c1s + pa2[3] * c2s) * inv);
    *(ushort4*)(orow + 4 * g) = o1;
    *(ushort4*)(orow + 16 + 4 * g) = o2;
  }
}

// ----------------------------------------------------------------
extern "C" void kernel_launch(void* const* d_in, const int* in_sizes, int n_in,
                              void* d_out, int out_size, void* d_ws, size_t ws_size,
                              hipStream_t stream) {
  (void)in_sizes; (void)n_in; (void)out_size; (void)ws_size;
  const float* s     = (const float*)d_in[0];
  const float* z     = (const float*)d_in[1];
  const unsigned* km = (const unsigned*)d_in[2];
  const float* Wq = (const float*)d_in[3];
  const float* bq = (const float*)d_in[4];
  const float* Wk = (const float*)d_in[5];
  const float* bk = (const float*)d_in[6];
  const float* Wv = (const float*)d_in[7];
  const float* bv = (const float*)d_in[8];
  const float* Wb = (const float*)d_in[9];
  const float* bb = (const float*)d_in[10];
  const float* Wg = (const float*)d_in[11];
  const float* bg = (const float*)d_in[12];
  const float* Wo = (const float*)d_in[13];
  const float* bo = (const float*)d_in[14];
  const float* gamma = (const float*)d_in[15];
  const float* beta  = (const float*)d_in[16];

  char* ws = (char*)d_ws;
  unsigned short* sn    = (unsigned short*)(ws);                 // 2 MB
  unsigned short* qbuf  = (unsigned short*)(ws + (2ull << 20));  // 2 MB [b n][512]
  unsigned short* kbuf  = (unsigned short*)(ws + (4ull << 20));  // 2 MB [b][h][m][d]
  unsigned short* vbuf  = (unsigned short*)(ws + (6ull << 20));  // 2 MB [b][h][d][m]
  float*          gate  = (float*)(ws + (8ull << 20));           // 4 MB
  unsigned short* aout  = (unsigned short*)(ws + (12ull << 20)); // 2 MB
  unsigned short* bias  = (unsigned short*)(ws + (14ull << 20)); // 64 MB [b][n][h][m]
  int*            maskc = (int*)(ws + (78ull << 20));            // 8 KB

  hipLaunchKernelGGL(k_mask, dim3(1), dim3(256), 0, stream, km, maskc);
  hipLaunchKernelGGL(k_ln, dim3(2048), dim3(64), 0, stream, s, gamma, beta, sn);
  hipLaunchKernelGGL(k_qkvg, dim3(4, 16, 4), dim3(256), 0, stream, sn,
                     Wq, Wk, Wv, Wg, bq, bk, bv, bg,
                     (void*)qbuf, (void*)kbuf, (void*)vbuf, (void*)gate);
  hipLaunchKernelGGL(k_bias, dim3(4096), dim3(256), 0, stream, z, Wb, bb, maskc, bias);
  hipLaunchKernelGGL(k_attn, dim3(16, 16, 2), dim3(512), 0, stream,
                     qbuf, kbuf, vbuf, bias, aout);
  hipLaunchKernelGGL(k_gemm_out, dim3(4, 16), dim3(256), 0, stream, aout, Wo, bo,
                     (float*)d_out, gate);
}

// Round 5
// 345.080 us; speedup vs baseline: 1.0381x; 1.0381x over previous
//
#include <hip/hip_runtime.h>
#include <hip/hip_fp16.h>

typedef __attribute__((ext_vector_type(8))) _Float16 f16x8;
typedef __attribute__((ext_vector_type(8))) unsigned short u16x8;
typedef __attribute__((ext_vector_type(4))) float f32x4;

#define DEV __device__ __forceinline__

DEV unsigned short f2h(float f) {
  _Float16 h = (_Float16)f;
  return __builtin_bit_cast(unsigned short, h);
}
DEV float h2f(unsigned short u) {
  return (float)__builtin_bit_cast(_Float16, u);
}
DEV unsigned pk(float lo, float hi) {
  return (unsigned)f2h(lo) | ((unsigned)f2h(hi) << 16);
}

// ---------------------------------------------------------------- prep:
// transpose-convert W (f32 [k][col]) -> Wt (f16 [col][k]) for 5 matrices,
// plus mask canonicalization in block (0,0).
__global__ __launch_bounds__(256) void k_prep(const float* __restrict__ W0, const float* __restrict__ W1,
                                              const float* __restrict__ W2, const float* __restrict__ W3,
                                              const float* __restrict__ W4,
                                              unsigned short* __restrict__ T0, unsigned short* __restrict__ T1,
                                              unsigned short* __restrict__ T2, unsigned short* __restrict__ T3,
                                              unsigned short* __restrict__ T4,
                                              const unsigned* __restrict__ raw, int* __restrict__ canon) {
  int mat = blockIdx.y;
  const float* W = (mat == 0) ? W0 : (mat == 1) ? W1 : (mat == 2) ? W2 : (mat == 3) ? W3 : W4;
  unsigned short* T = (mat == 0) ? T0 : (mat == 1) ? T1 : (mat == 2) ? T2 : (mat == 3) ? T3 : T4;
  int tx = blockIdx.x & 7, ty = blockIdx.x >> 3;  // col-tile, k-tile (64x64)
  __shared__ float tile[64][65];
  int t = threadIdx.x;
  int r = t >> 6, c = t & 63;
#pragma unroll
  for (int i = 0; i < 16; ++i)
    tile[r + i * 4][c] = W[(size_t)(ty * 64 + r + i * 4) * 512 + tx * 64 + c];
  __syncthreads();
#pragma unroll
  for (int i = 0; i < 16; ++i)
    T[(size_t)(tx * 64 + r + i * 4) * 512 + ty * 64 + c] = f2h(tile[c][r + i * 4]);

  if (mat == 0 && blockIdx.x == 0) {  // mask canon (block-uniform branch)
    __shared__ int s_gt1, s_f32;
    if (t == 0) { s_gt1 = 0; s_f32 = 0; }
    __syncthreads();
    int gt1 = 0, fv = 0;
    for (int i = t; i < 512; i += 256) {
      unsigned v = raw[i];
      if (v == 0x3F800000u) fv = 1;
      else if (v > 1u) gt1 = 1;
    }
    if (gt1) s_gt1 = 1;
    if (fv)  s_f32 = 1;
    __syncthreads();
    int mode = s_gt1 ? 1 : (s_f32 ? 2 : 0);
    for (int i = t; i < 2048; i += 256) {
      int v;
      if (mode == 1)      v = ((const unsigned char*)raw)[i] ? 1 : 0;
      else if (mode == 2) v = (((const float*)raw)[i] != 0.f) ? 1 : 0;
      else                v = raw[i] ? 1 : 0;
      canon[i] = v;
    }
  }
}

// ---------------------------------------------------------------- layernorm -> f16
__global__ __launch_bounds__(64) void k_ln(const float* __restrict__ s,
                                           const float* __restrict__ gamma,
                                           const float* __restrict__ beta,
                                           unsigned short* __restrict__ sn) {
  int row = blockIdx.x, l = threadIdx.x;
  const float* sr = s + (size_t)row * 512 + l * 8;
  float4 x0 = *(const float4*)sr, x1 = *(const float4*)(sr + 4);
  float sum = x0.x + x0.y + x0.z + x0.w + x1.x + x1.y + x1.z + x1.w;
  float sq  = x0.x*x0.x + x0.y*x0.y + x0.z*x0.z + x0.w*x0.w
            + x1.x*x1.x + x1.y*x1.y + x1.z*x1.z + x1.w*x1.w;
#pragma unroll
  for (int off = 32; off >= 1; off >>= 1) {
    sum += __shfl_xor(sum, off);
    sq  += __shfl_xor(sq, off);
  }
  float mu = sum * (1.f / 512.f);
  float rstd = rsqrtf(sq * (1.f / 512.f) - mu * mu + 1e-5f);
  float4 g0 = *(const float4*)(gamma + l * 8), g1 = *(const float4*)(gamma + l * 8 + 4);
  float4 b0 = *(const float4*)(beta + l * 8),  b1 = *(const float4*)(beta + l * 8 + 4);
  u16x8 o;
  o[0] = f2h((x0.x - mu) * rstd * g0.x + b0.x);
  o[1] = f2h((x0.y - mu) * rstd * g0.y + b0.y);
  o[2] = f2h((x0.z - mu) * rstd * g0.z + b0.z);
  o[3] = f2h((x0.w - mu) * rstd * g0.w + b0.w);
  o[4] = f2h((x1.x - mu) * rstd * g1.x + b1.x);
  o[5] = f2h((x1.y - mu) * rstd * g1.y + b1.y);
  o[6] = f2h((x1.z - mu) * rstd * g1.z + b1.z);
  o[7] = f2h((x1.w - mu) * rstd * g1.w + b1.w);
  *(u16x8*)(sn + (size_t)row * 512 + l * 8) = o;
}

// ---------------------------------------------------------------- direct-fragment GEMM
// A f16 [2048][512] k-contig; Wt f16 [col][k] k-contig. No LDS, no barriers.
// Block tile 128 rows x 64 cols; 4 waves as 2x2 (wave tile 64x32).
DEV void gemm_direct(const unsigned short* __restrict__ A,
                     const unsigned short* __restrict__ Wt,
                     const float* __restrict__ bvec,
                     void* __restrict__ outp,
                     const float* __restrict__ gate,
                     int mode, int ct, int rt) {
  int t = threadIdx.x, l = t & 63, w = t >> 6;
  int lane15 = l & 15, g = l >> 4;
  int wr = w >> 1, wc = w & 1;
  const unsigned short* ap[4];
  const unsigned short* bp[2];
#pragma unroll
  for (int mt = 0; mt < 4; ++mt)
    ap[mt] = A + (size_t)(rt * 128 + wr * 64 + mt * 16 + lane15) * 512 + g * 8;
#pragma unroll
  for (int nt = 0; nt < 2; ++nt)
    bp[nt] = Wt + (size_t)(ct * 64 + wc * 32 + nt * 16 + lane15) * 512 + g * 8;

  f32x4 acc[4][2];
#pragma unroll
  for (int mt = 0; mt < 4; ++mt)
#pragma unroll
    for (int nt = 0; nt < 2; ++nt) acc[mt][nt] = (f32x4){0.f, 0.f, 0.f, 0.f};

  f16x8 af[4], bf[2];
#pragma unroll
  for (int mt = 0; mt < 4; ++mt) af[mt] = *(const f16x8*)ap[mt];
#pragma unroll
  for (int nt = 0; nt < 2; ++nt) bf[nt] = *(const f16x8*)bp[nt];

  for (int ks = 0; ks < 16; ++ks) {
    f16x8 an[4], bn[2];
    if (ks < 15) {
#pragma unroll
      for (int mt = 0; mt < 4; ++mt) an[mt] = *(const f16x8*)(ap[mt] + (ks + 1) * 32);
#pragma unroll
      for (int nt = 0; nt < 2; ++nt) bn[nt] = *(const f16x8*)(bp[nt] + (ks + 1) * 32);
    } else {
#pragma unroll
      for (int mt = 0; mt < 4; ++mt) an[mt] = af[mt];
#pragma unroll
      for (int nt = 0; nt < 2; ++nt) bn[nt] = bf[nt];
    }
#pragma unroll
    for (int mt = 0; mt < 4; ++mt)
#pragma unroll
      for (int nt = 0; nt < 2; ++nt)
        acc[mt][nt] = __builtin_amdgcn_mfma_f32_16x16x32_f16(af[mt], bf[nt], acc[mt][nt], 0, 0, 0);
#pragma unroll
    for (int mt = 0; mt < 4; ++mt) af[mt] = an[mt];
#pragma unroll
    for (int nt = 0; nt < 2; ++nt) bf[nt] = bn[nt];
  }

#pragma unroll
  for (int mt = 0; mt < 4; ++mt)
#pragma unroll
    for (int nt = 0; nt < 2; ++nt) {
      int col = ct * 64 + wc * 32 + nt * 16 + lane15;
      float bv = bvec[col];
#pragma unroll
      for (int i = 0; i < 4; ++i) {
        int row = rt * 128 + wr * 64 + mt * 16 + g * 4 + i;
        float val = acc[mt][nt][i] + bv;
        int bb_ = row >> 10, n = row & 1023, hh = col >> 5, d = col & 31;
        if (mode == 0) {
          ((unsigned short*)outp)[(size_t)row * 512 + col] = f2h(val);
        } else if (mode == 1) {
          ((unsigned short*)outp)[(((size_t)bb_ * 16 + hh) * 1024 + n) * 32 + d] = f2h(val);
        } else if (mode == 2) {
          ((unsigned short*)outp)[(((size_t)bb_ * 16 + hh) * 32 + d) * 1024 + n] = f2h(val);
        } else if (mode == 3) {
          ((float*)outp)[(size_t)row * 512 + col] = 1.f / (1.f + __expf(-val));
        } else {
          ((float*)outp)[(size_t)row * 512 + col] = gate[(size_t)row * 512 + col] * val;
        }
      }
    }
}

__global__ __launch_bounds__(256) void k_qkvg(const unsigned short* __restrict__ A,
                                              const unsigned short* __restrict__ T0, const unsigned short* __restrict__ T1,
                                              const unsigned short* __restrict__ T2, const unsigned short* __restrict__ T3,
                                              const float* __restrict__ b0, const float* __restrict__ b1,
                                              const float* __restrict__ b2, const float* __restrict__ b3,
                                              void* o0, void* o1, void* o2, void* o3) {
  int mode = blockIdx.z;
  const unsigned short* Wt = (mode == 0) ? T0 : (mode == 1) ? T1 : (mode == 2) ? T2 : T3;
  const float* bv = (mode == 0) ? b0 : (mode == 1) ? b1 : (mode == 2) ? b2 : b3;
  void* o = (mode == 0) ? o0 : (mode == 1) ? o1 : (mode == 2) ? o2 : o3;
  gemm_direct(A, Wt, bv, o, nullptr, mode, blockIdx.x, blockIdx.y);
}

__global__ __launch_bounds__(256) void k_gemm_out(const unsigned short* __restrict__ A,
                                                  const unsigned short* __restrict__ Wt,
                                                  const float* __restrict__ bvec,
                                                  float* __restrict__ outp,
                                                  const float* __restrict__ gate) {
  gemm_direct(A, Wt, bvec, outp, gate, 4, blockIdx.x, blockIdx.y);
}

// ---------------------------------------------------------------- pair-bias stream
// bias[b][n][h][m] f16 = z[b,n,m,:]@Wb[:,h] + bb[h]; masked m -> -65504 sentinel.
// (round-4 structure, kept: wave-private LDS staging, no barriers)
__global__ __launch_bounds__(256, 4) void k_bias(const float* __restrict__ z,
                                                 const float* __restrict__ Wb,
                                                 const float* __restrict__ bbp,
                                                 const int* __restrict__ maskc,
                                                 unsigned short* __restrict__ bias) {
  int bid = blockIdx.x;             // 2*(b*1024+n) + half
  int slab = bid >> 1, half = bid & 1;
  int b = slab >> 10;
  int t = threadIdx.x, l = t & 63, w = t >> 6;
  int lane15 = l & 15, g = l >> 4;

  __shared__ float lds_[4][2048];   // 8 KB per wave
  float* wlds = lds_[w];

  f16x8 wf[4];
#pragma unroll
  for (int ks = 0; ks < 4; ++ks)
#pragma unroll
    for (int j = 0; j < 8; ++j)
      wf[ks][j] = (_Float16)Wb[(ks * 32 + g * 8 + j) * 16 + lane15];
  float bbh = bbp[lane15];

  const char* zb = (const char*)(z + ((size_t)slab * 1024 + half * 512 + (size_t)w * 128) * 128);
  unsigned short* ob = bias + ((size_t)slab * 16 + lane15) * 1024;
  const int* mrow = maskc + b * 1024;

  float4 rbuf[8];
#pragma unroll
  for (int i = 0; i < 8; ++i)
    rbuf[i] = *(const float4*)(zb + i * 1024 + l * 16);
#pragma unroll
  for (int i = 0; i < 8; ++i) {
    int lin = i * 1024 + l * 16;
    int off = lin ^ (((lin >> 9) & 7) << 4);
    *(float4*)((char*)wlds + off) = rbuf[i];
  }

  for (int t8 = 0; t8 < 8; ++t8) {
    if (t8 < 7) {
      const char* tb = zb + (t8 + 1) * 8192;
#pragma unroll
      for (int i = 0; i < 8; ++i)
        rbuf[i] = *(const float4*)(tb + i * 1024 + l * 16);
    }
    f32x4 acc = (f32x4){0.f, 0.f, 0.f, 0.f};
#pragma unroll
    for (int ks = 0; ks < 4; ++ks) {
      int linA = lane15 * 512 + ks * 128 + g * 32;
      int swz = ((lane15 & 7) << 4);
      float4 z0 = *(const float4*)((const char*)wlds + (linA ^ swz));
      float4 z1 = *(const float4*)((const char*)wlds + ((linA + 16) ^ swz));
      f16x8 af;
      af[0] = (_Float16)z0.x; af[1] = (_Float16)z0.y;
      af[2] = (_Float16)z0.z; af[3] = (_Float16)z0.w;
      af[4] = (_Float16)z1.x; af[5] = (_Float16)z1.y;
      af[6] = (_Float16)z1.z; af[7] = (_Float16)z1.w;
      acc = __builtin_amdgcn_mfma_f32_16x16x32_f16(af, wf[ks], acc, 0, 0, 0);
    }
    int mabs = half * 512 + w * 128 + t8 * 16 + 4 * g;
    int4 mk = *(const int4*)(mrow + mabs);
    ushort4 o4;
    o4.x = mk.x ? 0xFBFFu : f2h(acc[0] + bbh);
    o4.y = mk.y ? 0xFBFFu : f2h(acc[1] + bbh);
    o4.z = mk.z ? 0xFBFFu : f2h(acc[2] + bbh);
    o4.w = mk.w ? 0xFBFFu : f2h(acc[3] + bbh);
    *(ushort4*)(ob + mabs) = o4;
    if (t8 < 7) {
#pragma unroll
      for (int i = 0; i < 8; ++i) {
        int lin = i * 1024 + l * 16;
        int off = lin ^ (((lin >> 9) & 7) << 4);
        *(float4*)((char*)wlds + off) = rbuf[i];
      }
    }
  }
}

// ---------------------------------------------------------------- attention
// In-register flash, key-split (8 waves = 4 q-subtiles x 2 key-halves),
// software-pipelined chunk loads (K/bias/V for c+1 issued before compute of c).
struct Pf {
  f16x8 kf1, kf2, vf1, vf2;
  ushort4 bv1, bv2;
};
DEV Pf ldchunk(const unsigned short* kb_, const unsigned short* vb_,
               const unsigned short* brow, int lane15, int g, int c) {
  Pf p;
  int m0 = c * 32;
  p.kf1 = *(const f16x8*)(kb_ + (size_t)(m0 + lane15) * 32 + g * 8);
  p.kf2 = *(const f16x8*)(kb_ + (size_t)(m0 + 16 + lane15) * 32 + g * 8);
  p.bv1 = *(const ushort4*)(brow + m0 + 4 * g);
  p.bv2 = *(const ushort4*)(brow + m0 + 16 + 4 * g);
  p.vf1 = *(const f16x8*)(vb_ + (size_t)lane15 * 1024 + m0 + 8 * g);
  p.vf2 = *(const f16x8*)(vb_ + (size_t)(16 + lane15) * 1024 + m0 + 8 * g);
  return p;
}

__global__ __launch_bounds__(512, 4) void k_attn(const unsigned short* __restrict__ qbuf,
                                                 const unsigned short* __restrict__ kbuf,
                                                 const unsigned short* __restrict__ vbuf,
                                                 const unsigned short* __restrict__ bias,
                                                 unsigned short* __restrict__ aout) {
  int qt = blockIdx.x, h = blockIdx.y, b = blockIdx.z;
  int t = threadIdx.x, l = t & 63, w = t >> 6;
  int qs = w & 3, half = w >> 2;
  int q0 = (qt * 4 + qs) * 16;
  int lane15 = l & 15, g = l >> 4;
  int bh = b * 16 + h;
  const float RS = 0.17677669529663687f;  // 1/sqrt(32)

  __shared__ float red_m[4][64];
  __shared__ float red_l[4][64];
  __shared__ f32x4 red_a1[4][64];
  __shared__ f32x4 red_a2[4][64];

  f16x8 qf = *(const f16x8*)(qbuf + ((size_t)(b * 1024 + q0 + lane15)) * 512 + h * 32 + g * 8);

  const unsigned short* kb_ = kbuf + (size_t)bh * 1024 * 32 + (size_t)half * 512 * 32;
  const unsigned short* vb_ = vbuf + (size_t)bh * 32 * 1024 + half * 512;
  const unsigned short* brow = bias + ((size_t)(b * 1024 + q0 + lane15) * 16 + h) * 1024 + half * 512;

  float m_run = -3.0e38f, lsum = 0.f;
  f32x4 acc1 = (f32x4){0.f, 0.f, 0.f, 0.f};
  f32x4 acc2 = (f32x4){0.f, 0.f, 0.f, 0.f};

  Pf cur = ldchunk(kb_, vb_, brow, lane15, g, 0);

  for (int c = 0; c < 16; ++c) {
    Pf nxt = cur;
    if (c < 15) nxt = ldchunk(kb_, vb_, brow, lane15, g, c + 1);

    f32x4 zero = (f32x4){0.f, 0.f, 0.f, 0.f};
    f32x4 c1 = __builtin_amdgcn_mfma_f32_16x16x32_f16(cur.kf1, qf, zero, 0, 0, 0);
    f32x4 c2 = __builtin_amdgcn_mfma_f32_16x16x32_f16(cur.kf2, qf, zero, 0, 0, 0);
    float s1[4], s2[4];
    s1[0] = c1[0] * RS + h2f(cur.bv1.x); s1[1] = c1[1] * RS + h2f(cur.bv1.y);
    s1[2] = c1[2] * RS + h2f(cur.bv1.z); s1[3] = c1[3] * RS + h2f(cur.bv1.w);
    s2[0] = c2[0] * RS + h2f(cur.bv2.x); s2[1] = c2[1] * RS + h2f(cur.bv2.y);
    s2[2] = c2[2] * RS + h2f(cur.bv2.z); s2[3] = c2[3] * RS + h2f(cur.bv2.w);
    float cm = fmaxf(fmaxf(fmaxf(s1[0], s1[1]), fmaxf(s1[2], s1[3])),
                     fmaxf(fmaxf(s2[0], s2[1]), fmaxf(s2[2], s2[3])));
    cm = fmaxf(cm, __shfl_xor(cm, 16));
    cm = fmaxf(cm, __shfl_xor(cm, 32));
    float mn = fmaxf(m_run, cm);
    float corr = __expf(m_run - mn);
    m_run = mn;
    float p1[4], p2[4], csum = 0.f;
#pragma unroll
    for (int i = 0; i < 4; ++i) { p1[i] = __expf(s1[i] - mn); csum += p1[i]; }
#pragma unroll
    for (int i = 0; i < 4; ++i) { p2[i] = __expf(s2[i] - mn); csum += p2[i]; }
    lsum = lsum * corr + csum;
#pragma unroll
    for (int i = 0; i < 4; ++i) { acc1[i] *= corr; acc2[i] *= corr; }
    unsigned a0 = pk(p1[0], p1[1]), a1 = pk(p1[2], p1[3]);
    unsigned b0 = pk(p2[0], p2[1]), b1 = pk(p2[2], p2[3]);
    int s0 = ((g & 1) << 5) + lane15, s1l = s0 + 16;
    unsigned wA0 = (unsigned)__shfl((int)a0, s0);
    unsigned wA1 = (unsigned)__shfl((int)a1, s0);
    unsigned wA2 = (unsigned)__shfl((int)a0, s1l);
    unsigned wA3 = (unsigned)__shfl((int)a1, s1l);
    unsigned wB0 = (unsigned)__shfl((int)b0, s0);
    unsigned wB1 = (unsigned)__shfl((int)b1, s0);
    unsigned wB2 = (unsigned)__shfl((int)b0, s1l);
    unsigned wB3 = (unsigned)__shfl((int)b1, s1l);
    bool hi = (l & 32) != 0;
    union { unsigned u[4]; f16x8 v; } pu;
    pu.u[0] = hi ? wB0 : wA0;
    pu.u[1] = hi ? wB1 : wA1;
    pu.u[2] = hi ? wB2 : wA2;
    pu.u[3] = hi ? wB3 : wA3;
    acc1 = __builtin_amdgcn_mfma_f32_16x16x32_f16(cur.vf1, pu.v, acc1, 0, 0, 0);
    acc2 = __builtin_amdgcn_mfma_f32_16x16x32_f16(cur.vf2, pu.v, acc2, 0, 0, 0);
    cur = nxt;
  }

  lsum += __shfl_xor(lsum, 16);
  lsum += __shfl_xor(lsum, 32);

  if (half) {
    red_m[qs][l] = m_run;
    red_l[qs][l] = lsum;
    red_a1[qs][l] = acc1;
    red_a2[qs][l] = acc2;
  }
  __syncthreads();
  if (!half) {
    float pm = red_m[qs][l], plv = red_l[qs][l];
    f32x4 pa1 = red_a1[qs][l], pa2 = red_a2[qs][l];
    float mm = fmaxf(m_run, pm);
    float c1s = __expf(m_run - mm), c2s = __expf(pm - mm);
    float lt = lsum * c1s + plv * c2s;
    float inv = (mm > -30000.f && lt > 0.f) ? 1.f / lt : 0.f;
    unsigned short* orow = aout + ((size_t)(b * 1024 + q0 + lane15)) * 512 + h * 32;
    ushort4 o1, o2;
    o1.x = f2h((acc1[0] * c1s + pa1[0] * c2s) * inv);
    o1.y = f2h((acc1[1] * c1s + pa1[1] * c2s) * inv);
    o1.z = f2h((acc1[2] * c1s + pa1[2] * c2s) * inv);
    o1.w = f2h((acc1[3] * c1s + pa1[3] * c2s) * inv);
    o2.x = f2h((acc2[0] * c1s + pa2[0] * c2s) * inv);
    o2.y = f2h((acc2[1] * c1s + pa2[1] * c2s) * inv);
    o2.z = f2h((acc2[2] * c1s + pa2[2] * c2s) * inv);
    o2.w = f2h((acc2[3] * c1s + pa2[3] * c2s) * inv);
    *(ushort4*)(orow + 4 * g) = o1;
    *(ushort4*)(orow + 16 + 4 * g) = o2;
  }
}

// ----------------------------------------------------------------
extern "C" void kernel_launch(void* const* d_in, const int* in_sizes, int n_in,
                              void* d_out, int out_size, void* d_ws, size_t ws_size,
                              hipStream_t stream) {
  (void)in_sizes; (void)n_in; (void)out_size; (void)ws_size;
  const float* s     = (const float*)d_in[0];
  const float* z     = (const float*)d_in[1];
  const unsigned* km = (const unsigned*)d_in[2];
  const float* Wq = (const float*)d_in[3];
  const float* bq = (const float*)d_in[4];
  const float* Wk = (const float*)d_in[5];
  const float* bk = (const float*)d_in[6];
  const float* Wv = (const float*)d_in[7];
  const float* bv = (const float*)d_in[8];
  const float* Wb = (const float*)d_in[9];
  const float* bb = (const float*)d_in[10];
  const float* Wg = (const float*)d_in[11];
  const float* bg = (const float*)d_in[12];
  const float* Wo = (const float*)d_in[13];
  const float* bo = (const float*)d_in[14];
  const float* gamma = (const float*)d_in[15];
  const float* beta  = (const float*)d_in[16];

  char* ws = (char*)d_ws;
  unsigned short* sn    = (unsigned short*)(ws);                 // 2 MB
  unsigned short* qbuf  = (unsigned short*)(ws + (2ull << 20));  // 2 MB [b n][512]
  unsigned short* kbuf  = (unsigned short*)(ws + (4ull << 20));  // 2 MB [b][h][m][d]
  unsigned short* vbuf  = (unsigned short*)(ws + (6ull << 20));  // 2 MB [b][h][d][m]
  float*          gate  = (float*)(ws + (8ull << 20));           // 4 MB
  unsigned short* aout  = (unsigned short*)(ws + (12ull << 20)); // 2 MB
  unsigned short* bias  = (unsigned short*)(ws + (14ull << 20)); // 64 MB [b][n][h][m]
  int*            maskc = (int*)(ws + (78ull << 20));            // 8 KB
  unsigned short* wtq   = (unsigned short*)(ws + (80ull << 20));            // 512 KB each
  unsigned short* wtk   = (unsigned short*)(ws + (80ull << 20) + (512u << 10));
  unsigned short* wtv   = (unsigned short*)(ws + (80ull << 20) + (1024u << 10));
  unsigned short* wtg   = (unsigned short*)(ws + (80ull << 20) + (1536u << 10));
  unsigned short* wto   = (unsigned short*)(ws + (80ull << 20) + (2048u << 10));

  hipLaunchKernelGGL(k_prep, dim3(64, 5), dim3(256), 0, stream,
                     Wq, Wk, Wv, Wg, Wo, wtq, wtk, wtv, wtg, wto, km, maskc);
  hipLaunchKernelGGL(k_ln, dim3(2048), dim3(64), 0, stream, s, gamma, beta, sn);
  hipLaunchKernelGGL(k_qkvg, dim3(8, 16, 4), dim3(256), 0, stream, sn,
                     wtq, wtk, wtv, wtg, bq, bk, bv, bg,
                     (void*)qbuf, (void*)kbuf, (void*)vbuf, (void*)gate);
  hipLaunchKernelGGL(k_bias, dim3(4096), dim3(256), 0, stream, z, Wb, bb, maskc, bias);
  hipLaunchKernelGGL(k_attn, dim3(16, 16, 2), dim3(512), 0, stream,
                     qbuf, kbuf, vbuf, bias, aout);
  hipLaunchKernelGGL(k_gemm_out, dim3(8, 16), dim3(256), 0, stream, aout, wto, bo,
                     (float*)d_out, gate);
}